// Round 4
// baseline (378.283 us; speedup 1.0000x reference)
//
#include <hip/hip_runtime.h>

// ConvCRF forward, MI355X — round 4: single PLAIN launch + manual grid barrier.
// Round-3 post-mortem: hipLaunchCooperativeKernel never executed (d_out untouched,
// absmax identical to the empty-stub round). Plain launches are proven; grid sync
// is done manually with device-scope atomics in d_ws.
//
// Co-residency argument (required for the barrier): grid = 200 blocks <= 256 CUs,
// static LDS 49.5 KB < 64 KB, __launch_bounds__(256,1) -> every CU can host >= 1
// block, so the dispatcher makes all 200 blocks resident before any completes.
//
// Barrier protocol (poison-tolerant, graph-replay-safe):
//  - init: block(0,0,0) stores counter=0 then release-stores flag=MAGIC; all
//    blocks acquire-spin on flag==MAGIC before first use of counter. Works for
//    any initial ws contents (harness poisons ws to 0xAA before every launch).
//  - barrier k: all threads __threadfence() (agent release -> L2 writeback,
//    cross-XCD), thread0 atomicAdd(counter)+spin until >= 200*k, then all
//    threads __threadfence() (agent acquire -> L1/L2 invalidate) + syncthreads.
//
// Compute per iteration (validated logic from round 2):
//  22x22 halo batch-axis softmax (reference does softmax over axis=0 = BATCH!)
//  -> LDS float4 channel planes -> branch-free 7x7 dual-filter taps with
//  channel-independent norms -> 19x38 matvec (M=[compat@sw|compat@bw] in LDS)
//  -> q = u - pairwise. q ping-pongs through padded-20ch float4 ws buffers;
//  iter 0 reads u directly, iter 4 writes d_out.

#define HH 160
#define WW 160
#define NPIX (HH*WW)     // 25600
#define NC 19
#define CH 20            // padded channels
#define NG 5             // CH/4
#define SPAN 3
#define TILE 16
#define LT 22            // TILE + 2*SPAN
#define NHALO (LT*LT)    // 484
#define NBLK 200
#define EPSF 1e-20f
#define MAGICV 0x5EEDF00Du

__device__ __forceinline__ float fast_rcp(float x) { return __builtin_amdgcn_rcpf(x); }

__device__ __forceinline__ float smx(float q0, float q1, int b) {
    const float m  = fmaxf(q0, q1);
    const float e0 = __expf(q0 - m);
    const float e1 = __expf(q1 - m);
    return (b == 0 ? e0 : e1) * fast_rcp(e0 + e1);
}

__device__ __forceinline__ float ldch(const float* base, int c) {
    return (c < NC) ? base[c] : 0.0f;
}

__device__ __forceinline__ void grid_barrier(unsigned* cnt, unsigned target) {
    __syncthreads();
    __threadfence();                       // release: writeback (cross-XCD visible)
    if (threadIdx.x == 0) {
        __hip_atomic_fetch_add(cnt, 1u, __ATOMIC_ACQ_REL, __HIP_MEMORY_SCOPE_AGENT);
        while (__hip_atomic_load(cnt, __ATOMIC_ACQUIRE, __HIP_MEMORY_SCOPE_AGENT) < target)
            __builtin_amdgcn_s_sleep(2);
    }
    __syncthreads();
    __threadfence();                       // acquire: invalidate stale cached q
}

__global__ void __launch_bounds__(256, 1) crf_kernel(
        const float* __restrict__ u,      // (2,160,160,19)
        const float* __restrict__ rgb,    // (2,160,160,3)
        const float* __restrict__ sw, const float* __restrict__ bw,
        const float* __restrict__ compat,
        float4* __restrict__ qA, float4* __restrict__ qB,
        unsigned* __restrict__ bar,       // [0]=flag, [1]=counter
        float*  __restrict__ out) {
    __shared__ float4 smL[NG * NHALO];
    __shared__ float4 rgbL[NHALO];
    __shared__ float  ML[NC * 40];

    const int b   = blockIdx.z;
    const int ti0 = blockIdx.y * TILE;
    const int tj0 = blockIdx.x * TILE;
    const int tid = threadIdx.x;
    const int ty  = tid >> 4, tx = tid & 15;
    const int i   = ti0 + ty, j = tj0 + tx;
    const int li  = ty + SPAN, lj = tx + SPAN;
    const int myp = i * WW + j;

    // ---- barrier init handshake (poison-tolerant) ----
    if ((blockIdx.x | blockIdx.y | blockIdx.z) == 0 && tid == 0) {
        __hip_atomic_store(&bar[1], 0u, __ATOMIC_RELAXED, __HIP_MEMORY_SCOPE_AGENT);
        __hip_atomic_store(&bar[0], MAGICV, __ATOMIC_RELEASE, __HIP_MEMORY_SCOPE_AGENT);
    }
    if (tid == 0) {
        while (__hip_atomic_load(&bar[0], __ATOMIC_ACQUIRE, __HIP_MEMORY_SCOPE_AGENT) != MAGICV)
            __builtin_amdgcn_s_sleep(2);
    }
    __syncthreads();

    // ---- one-time: M = [compat@sw | compat@bw] (cols 19,39 stay 0) ----
    for (int e = tid; e < NC * 40; e += 256) {
        const int k = e / 40, c = e % 40;
        float acc = 0.0f;
        if (c < NC) {
            for (int jj = 0; jj < NC; ++jj) acc += compat[k*NC + jj] * sw[jj*NC + c];
        } else if (c >= CH && c < CH + NC) {
            const int cc = c - CH;
            for (int jj = 0; jj < NC; ++jj) acc += compat[k*NC + jj] * bw[jj*NC + cc];
        }
        ML[e] = acc;
    }

    // ---- one-time: rgb halo (pre-scaled by 1/160, .w = validity mask) ----
    for (int e = tid; e < NHALO; e += 256) {
        const int r = e / LT, c2 = e % LT;
        const int gi = ti0 - SPAN + r, gj = tj0 - SPAN + c2;
        float4 rv = make_float4(0.f, 0.f, 0.f, 0.f);
        if (gi >= 0 && gi < HH && gj >= 0 && gj < WW) {
            const float* p = rgb + ((size_t)(b * NPIX) + gi * WW + gj) * 3;
            rv = make_float4(p[0] * (1.0f/160.0f), p[1] * (1.0f/160.0f),
                             p[2] * (1.0f/160.0f), 1.0f);
        }
        rgbL[e] = rv;
    }

    // ---- one-time: own-pixel unaries ----
    float uv[NC];
    {
        const float* up = u + ((size_t)(b * NPIX) + myp) * NC;
        #pragma unroll
        for (int c = 0; c < NC; ++c) uv[c] = up[c];
    }

    for (int it = 0; it < 5; ++it) {
        if (it > 0) grid_barrier(&bar[1], (unsigned)(NBLK * it));

        // ---- halo load + fused batch-axis softmax ----
        const float4* qsrc = (it & 1) ? qA : qB;
        for (int e = tid; e < NHALO; e += 256) {
            const int r = e / LT, c2 = e % LT;
            const int gi = ti0 - SPAN + r, gj = tj0 - SPAN + c2;
            if (gi >= 0 && gi < HH && gj >= 0 && gj < WW) {
                const int p = gi * WW + gj;
                if (it == 0) {
                    const float* q0 = u + (size_t)p * NC;
                    const float* q1 = u + (size_t)(NPIX + p) * NC;
                    #pragma unroll
                    for (int g = 0; g < NG; ++g) {
                        float4 o;
                        o.x = smx(ldch(q0, 4*g+0), ldch(q1, 4*g+0), b);
                        o.y = smx(ldch(q0, 4*g+1), ldch(q1, 4*g+1), b);
                        o.z = smx(ldch(q0, 4*g+2), ldch(q1, 4*g+2), b);
                        o.w = smx(ldch(q0, 4*g+3), ldch(q1, 4*g+3), b);
                        smL[g * NHALO + e] = o;
                    }
                } else {
                    const float4* q0 = qsrc + (size_t)p * NG;
                    const float4* q1 = qsrc + (size_t)(NPIX + p) * NG;
                    #pragma unroll
                    for (int g = 0; g < NG; ++g) {
                        const float4 a = q0[g];
                        const float4 d = q1[g];
                        float4 o;
                        o.x = smx(a.x, d.x, b);
                        o.y = smx(a.y, d.y, b);
                        o.z = smx(a.z, d.z, b);
                        o.w = smx(a.w, d.w, b);
                        smL[g * NHALO + e] = o;
                    }
                }
            } else {
                #pragma unroll
                for (int g = 0; g < NG; ++g) smL[g * NHALO + e] = make_float4(0,0,0,0);
            }
        }
        __syncthreads();

        // ---- 49-tap dual-filter accumulation ----
        const float4 crv = rgbL[li * LT + lj];
        float sa[CH], ba[CH];
        #pragma unroll
        for (int c = 0; c < CH; ++c) { sa[c] = 0.0f; ba[c] = 0.0f; }
        float s_n = 0.0f, b_n = 0.0f;

        for (int dx = -SPAN; dx <= SPAN; ++dx) {
            const int rowb = (li + dx) * LT + lj;
            #pragma unroll
            for (int dy = -SPAN; dy <= SPAN; ++dy) {
                const int noff = rowb + dy;
                const float4 rv = rgbL[noff];
                const float wsp = __expf(-0.5f * (float)(dx*dx + dy*dy) * (1.0f/9.0f)) * rv.w;
                const float dr = crv.x - rv.x, dg = crv.y - rv.y, db = crv.z - rv.z;
                const float wb = wsp * __expf(-0.5f * (dr*dr + dg*dg + db*db));
                s_n += wsp;
                b_n += wb;
                #pragma unroll
                for (int g = 0; g < NG; ++g) {
                    const float4 v = smL[g * NHALO + noff];
                    sa[4*g+0] += wsp * v.x; sa[4*g+1] += wsp * v.y;
                    sa[4*g+2] += wsp * v.z; sa[4*g+3] += wsp * v.w;
                    ba[4*g+0] += wb  * v.x; ba[4*g+1] += wb  * v.y;
                    ba[4*g+2] += wb  * v.z; ba[4*g+3] += wb  * v.w;
                }
            }
        }

        const float sinv = fast_rcp(s_n + EPSF);
        const float binv = fast_rcp(b_n + EPSF);
        #pragma unroll
        for (int c = 0; c < CH; ++c) { sa[c] *= sinv; ba[c] *= binv; }

        // ---- epilogue: q = u - (Ms*s + Mb*b) ----
        float outv[CH];
        #pragma unroll
        for (int k = 0; k < NC; ++k) {
            const float* mk = &ML[k * 40];
            float pw = 0.0f;
            #pragma unroll
            for (int c = 0; c < NC; ++c) pw += mk[c] * sa[c] + mk[CH + c] * ba[c];
            outv[k] = uv[k] - pw;
        }
        outv[NC] = 0.0f;

        if (it == 4) {
            float* op = out + ((size_t)(b * NPIX) + myp) * NC;
            #pragma unroll
            for (int k = 0; k < NC; ++k) op[k] = outv[k];
        } else {
            float4* dst = (it & 1) ? qB : qA;
            float4* op = dst + ((size_t)(b * NPIX) + myp) * NG;
            #pragma unroll
            for (int g = 0; g < NG; ++g)
                op[g] = make_float4(outv[4*g+0], outv[4*g+1], outv[4*g+2], outv[4*g+3]);
        }
    }
}

extern "C" void kernel_launch(void* const* d_in, const int* in_sizes, int n_in,
                              void* d_out, int out_size, void* d_ws, size_t ws_size,
                              hipStream_t stream) {
    const float* u      = (const float*)d_in[0];
    const float* rgb    = (const float*)d_in[1];
    const float* sw     = (const float*)d_in[2];
    const float* bw     = (const float*)d_in[3];
    const float* compat = (const float*)d_in[4];
    float* out = (float*)d_out;

    float4*   qA  = (float4*)d_ws;                    // 4,096,000 B
    float4*   qB  = qA + (size_t)2 * NPIX * NG;       // 4,096,000 B
    unsigned* bar = (unsigned*)((char*)d_ws + (8u << 20));  // own cache line at 8 MB

    crf_kernel<<<dim3(WW/TILE, HH/TILE, 2), dim3(256), 0, stream>>>(
        u, rgb, sw, bw, compat, qA, qB, bar, out);
}

// Round 6
// 287.882 us; speedup vs baseline: 1.3140x; 1.3140x over previous
//
#include <hip/hip_runtime.h>

// ConvCRF forward, MI355X — round 6: fused single-pass, PROVEN-scale grid.
// R5 post-mortem: hang (harness timeout) — 800-block grid barrier required 4
// blocks/CU co-residency; only 200 blocks (R4) is empirically proven. This round
// keeps grid=200 and scales occupancy via block WIDTH: 640 threads = 10 waves
// (2000 waves ~ 2/SIMD, 2.5x R4).
//
// Thread mapping: thread t -> (pixel-pair pp = t%128, channel-group g = t/128).
// Pair = two adjacent columns of the 16x16 tile -> paired LDS reads.
// Cycle-sink fixes vs R4 (328us):
//  - sm stored f16 (half4/group) -> halves tap LDS traffic (the binding pipe).
//  - bilateral weights wb: ITERATION-INVARIANT -> f16 cache [tap][px] in LDS,
//    computed once. Spatial weights = compile-time literals. OOB masking folds
//    into sm=0 at invalid halo positions -> hot loop has ZERO exp, ZERO masks.
//  - norms sn,bn iteration-invariant -> inverse norms in registers.
//  - epilogue M=[compat@sw|compat@bw] (20x40, zero-padded) from GLOBAL ws via
//    wave-uniform s_loads (readfirstlane on g) -> no LDS broadcast storm.
//  - grid barrier: R4-proven protocol, fences once per block (tid0; sound:
//    __syncthreads drains vmcnt per wave + write-through L1 => one wbl2/inv
//    per block covers all its traffic).
// LDS 47.6KB: region A (20,480B) = rgbL(precompute) -> smH(per-iter) ->
// accH(epilogue) time-shared; wbH 25,088B; snbL 2,048B.

#define HH 160
#define WW 160
#define NPIX (HH*WW)
#define NC 19
#define NG 5
#define SPAN 3
#define TS 16
#define LT 22              // TS + 2*SPAN
#define NHALO (LT*LT)      // 484
#define NBLK 200
#define NTHR 640
#define EPSF 1e-20f
#define MAGICV 0x5EEDF00Du

typedef __attribute__((ext_vector_type(4))) _Float16 half4;
typedef __attribute__((ext_vector_type(2))) _Float16 half2f;
typedef __attribute__((ext_vector_type(8))) _Float16 half8;

// exp(-(dx*dx+dy*dy)/18) literals, s = dx^2+dy^2
#define E0  1.0f
#define E1  0.94595947f
#define E2  0.89483932f
#define E4  0.80073740f
#define E5  0.75746513f
#define E8  0.64118039f
#define E9  0.60653066f
#define E10 0.57375342f
#define E13 0.48567179f
#define E18 0.36787944f
__device__ const float WSP[49] = {
    E18,E13,E10,E9,E10,E13,E18,
    E13,E8, E5, E4, E5, E8, E13,
    E10,E5, E2, E1, E2, E5, E10,
    E9, E4, E1, E0, E1, E4, E9,
    E10,E5, E2, E1, E2, E5, E10,
    E13,E8, E5, E4, E5, E8, E13,
    E18,E13,E10,E9,E10,E13,E18 };

// LDS byte offsets
#define OFF_A   0
#define SZ_A    20480                 // max(rgbL 7744, smH 19360, accH 20480)
#define OFF_WB  (OFF_A + SZ_A)
#define SZ_WB   (49*256*2)            // 25088
#define OFF_SNB (OFF_WB + SZ_WB)
#define LDS_TOT (OFF_SNB + 128*16)    // 47616

__device__ __forceinline__ float fast_rcp(float x) { return __builtin_amdgcn_rcpf(x); }

__device__ __forceinline__ float smx(float q0, float q1, int b) {
    const float m  = fmaxf(q0, q1);
    const float e0 = __expf(q0 - m);
    const float e1 = __expf(q1 - m);
    return (b ? e1 : e0) * fast_rcp(e0 + e1);
}

__global__ __launch_bounds__(800) void prep_kernel(
        const float* __restrict__ sw, const float* __restrict__ bw,
        const float* __restrict__ compat, float* __restrict__ M) {
    const int e = threadIdx.x;           // 20 rows x 40 cols
    if (e >= 800) return;
    const int k = e / 40, c = e % 40;
    float acc = 0.0f;
    if (k < NC) {
        if (c < NC) {
            for (int j = 0; j < NC; ++j) acc += compat[k*NC + j] * sw[j*NC + c];
        } else if (c >= 20 && c < 20 + NC) {
            for (int j = 0; j < NC; ++j) acc += compat[k*NC + j] * bw[j*NC + (c - 20)];
        }
    }
    M[e] = acc;    // rows/cols beyond 19 stay 0 -> pad channel fully masked
}

__global__ void __launch_bounds__(NTHR) crf_kernel(
        const float* __restrict__ u,      // (2,160,160,19)
        const float* __restrict__ rgb,    // (2,160,160,3)
        const float* __restrict__ M,      // (20,40) in ws
        float4* __restrict__ qA, float4* __restrict__ qB,
        unsigned* __restrict__ bar,       // [0]=flag,[1]=counter
        float* __restrict__ out) {
    __shared__ __align__(16) char shm[LDS_TOT];
    float4*   rgbL = (float4*)(shm + OFF_A);     // 484 (precompute phase only)
    half4*    smH  = (half4*)(shm + OFF_A);      // [g][halo pos], 5*484
    _Float16* accH = (_Float16*)(shm + OFF_A);   // [px][40] (epilogue phase)
    _Float16* wbH  = (_Float16*)(shm + OFF_WB);  // [tap][px], 49*256
    float4*   snbL = (float4*)(shm + OFF_SNB);   // [pair] = (snI0,bnI0,snI1,bnI1)

    const int tid = threadIdx.x;
    const int pp  = tid & 127;            // pixel pair
    const int g   = tid >> 7;             // channel group 0..4
    const int gu  = __builtin_amdgcn_readfirstlane(g);   // wave-uniform
    const int r   = pp >> 3;              // tile row 0..15
    const int c2  = (pp & 7) * 2;         // tile col (even) 0..14
    const int b   = blockIdx.z;
    const int ti0 = blockIdx.y * TS, tj0 = blockIdx.x * TS;
    const int px0l = r * TS + c2;         // local pixel idx of pair's first px
    const int gp0  = b * NPIX + (ti0 + r) * WW + (tj0 + c2);   // global (batched)
    const int p0   = (ti0 + r) * WW + (tj0 + c2);              // global (spatial)

    // ---- barrier init handshake (ws re-poisoned 0xAA before every launch) ----
    if ((blockIdx.x | blockIdx.y | blockIdx.z) == 0 && tid == 0) {
        __hip_atomic_store(&bar[1], 0u, __ATOMIC_RELAXED, __HIP_MEMORY_SCOPE_AGENT);
        __hip_atomic_store(&bar[0], MAGICV, __ATOMIC_RELEASE, __HIP_MEMORY_SCOPE_AGENT);
    }
    if (tid == 0) {
        while (__hip_atomic_load(&bar[0], __ATOMIC_ACQUIRE, __HIP_MEMORY_SCOPE_AGENT) != MAGICV)
            __builtin_amdgcn_s_sleep(2);
    }
    __syncthreads();

    // ---- phase 1: rgb halo into LDS (scaled 1/160, .w = validity) ----
    for (int e = tid; e < NHALO; e += NTHR) {
        const int hr = e / LT, hc = e % LT;
        const int gi = ti0 - SPAN + hr, gj = tj0 - SPAN + hc;
        float4 rv = make_float4(0.f, 0.f, 0.f, 0.f);
        if (gi >= 0 && gi < HH && gj >= 0 && gj < WW) {
            const float* p = rgb + ((size_t)(b * NPIX) + gi * WW + gj) * 3;
            rv = make_float4(p[0]*(1.f/160.f), p[1]*(1.f/160.f), p[2]*(1.f/160.f), 1.f);
        }
        rgbL[e] = rv;
    }
    __syncthreads();

    // ---- phase 2: per-(px,tap) bilateral weights + per-px inverse norms ----
    if (tid < 128) {
        const int ctr0 = (r + SPAN) * LT + (c2 + SPAN);
        const float4 cv0 = rgbL[ctr0];
        const float4 cv1 = rgbL[ctr0 + 1];
        float sn0 = 0.f, bn0 = 0.f, sn1 = 0.f, bn1 = 0.f;
        #pragma unroll
        for (int dx = -SPAN; dx <= SPAN; ++dx) {
            #pragma unroll
            for (int dy = -SPAN; dy <= SPAN; ++dy) {
                const int t = (dx+SPAN)*7 + (dy+SPAN);
                const int n = ctr0 + dx*LT + dy;
                const float ws = WSP[t];
                {
                    const float4 nv = rgbL[n];
                    const float wsm = ws * nv.w;
                    const float dr = cv0.x-nv.x, dg = cv0.y-nv.y, db = cv0.z-nv.z;
                    const float wb = wsm * __expf(-0.5f*(dr*dr+dg*dg+db*db));
                    wbH[t*256 + px0l] = (_Float16)wb;
                    sn0 += wsm; bn0 += wb;
                }
                {
                    const float4 nv = rgbL[n + 1];
                    const float wsm = ws * nv.w;
                    const float dr = cv1.x-nv.x, dg = cv1.y-nv.y, db = cv1.z-nv.z;
                    const float wb = wsm * __expf(-0.5f*(dr*dr+dg*dg+db*db));
                    wbH[t*256 + px0l + 1] = (_Float16)wb;
                    sn1 += wsm; bn1 += wb;
                }
            }
        }
        snbL[pp] = make_float4(fast_rcp(sn0+EPSF), fast_rcp(bn0+EPSF),
                               fast_rcp(sn1+EPSF), fast_rcp(bn1+EPSF));
    }

    // ---- one-time: own unary channels (group g, both pixels) ----
    float uv0[4], uv1[4];
    #pragma unroll
    for (int i = 0; i < 4; ++i) {
        const int ch = 4*g + i;
        uv0[i] = (ch < NC) ? u[(size_t)gp0 * NC + ch] : 0.0f;
        uv1[i] = (ch < NC) ? u[(size_t)(gp0 + 1) * NC + ch] : 0.0f;
    }
    __syncthreads();
    const float4 nv4 = snbL[pp];
    const float snI0 = nv4.x, bnI0 = nv4.y, snI1 = nv4.z, bnI1 = nv4.w;

    for (int it = 0; it < 5; ++it) {
        if (it > 0) {       // grid barrier (incl. per-block agent fences)
            __syncthreads();
            if (tid == 0) {
                __threadfence();
                __hip_atomic_fetch_add(&bar[1], 1u, __ATOMIC_ACQ_REL, __HIP_MEMORY_SCOPE_AGENT);
                while (__hip_atomic_load(&bar[1], __ATOMIC_ACQUIRE, __HIP_MEMORY_SCOPE_AGENT)
                       < (unsigned)(NBLK * it))
                    __builtin_amdgcn_s_sleep(2);
                __threadfence();
            }
            __syncthreads();
        }

        // ---- stage softmax (batch axis!) into f16 LDS planes ----
        const float4* qsrc = (it & 1) ? qA : qB;
        #pragma unroll
        for (int k = 0; k < 4; ++k) {
            const int e = tid + NTHR * k;
            if (e < NG * NHALO) {
                const int sg = e / NHALO, pos = e - sg * NHALO;
                const int hr = pos / LT, hc = pos % LT;
                const int gi = ti0 - SPAN + hr, gj = tj0 - SPAN + hc;
                half4 hv = (half4)(_Float16)0.0f;
                if (gi >= 0 && gi < HH && gj >= 0 && gj < WW) {
                    const int p = gi * WW + gj;
                    float s0, s1, s2, s3;
                    if (it == 0) {
                        const float* q0 = u + (size_t)p * NC;
                        const float* q1 = u + (size_t)(NPIX + p) * NC;
                        float a[4], d[4];
                        #pragma unroll
                        for (int i = 0; i < 4; ++i) {
                            const int ch = 4*sg + i;
                            a[i] = (ch < NC) ? q0[ch] : 0.0f;
                            d[i] = (ch < NC) ? q1[ch] : 0.0f;
                        }
                        s0 = smx(a[0],d[0],b); s1 = smx(a[1],d[1],b);
                        s2 = smx(a[2],d[2],b); s3 = smx(a[3],d[3],b);
                    } else {
                        const float4 a4 = qsrc[(size_t)p * NG + sg];
                        const float4 d4 = qsrc[(size_t)(NPIX + p) * NG + sg];
                        s0 = smx(a4.x,d4.x,b); s1 = smx(a4.y,d4.y,b);
                        s2 = smx(a4.z,d4.z,b); s3 = smx(a4.w,d4.w,b);
                    }
                    hv = (half4){(_Float16)s0, (_Float16)s1, (_Float16)s2, (_Float16)s3};
                }
                smH[sg * NHALO + pos] = hv;
            }
        }
        __syncthreads();

        // ---- 49 taps, both pixels, 4 channels; no exp, no masks ----
        float sA0=0,sA1=0,sA2=0,sA3=0, bA0=0,bA1=0,bA2=0,bA3=0;
        float sB0=0,sB1=0,sB2=0,sB3=0, bB0=0,bB1=0,bB2=0,bB3=0;
        const int ctr0 = (r + SPAN) * LT + (c2 + SPAN);
        const half4* pl = smH + g * NHALO;
        #pragma unroll
        for (int dx = -SPAN; dx <= SPAN; ++dx) {
            #pragma unroll
            for (int dy = -SPAN; dy <= SPAN; ++dy) {
                const int t = (dx+SPAN)*7 + (dy+SPAN);
                const int n = ctr0 + dx*LT + dy;
                const float ws = WSP[t];
                const half2f wbp = *(const half2f*)(wbH + t*256 + px0l);
                const float wb0 = (float)wbp.x, wb1 = (float)wbp.y;
                const half4 v0 = pl[n];
                const half4 v1 = pl[n + 1];
                const float f00=(float)v0.x, f01=(float)v0.y, f02=(float)v0.z, f03=(float)v0.w;
                const float f10=(float)v1.x, f11=(float)v1.y, f12=(float)v1.z, f13=(float)v1.w;
                sA0 += ws*f00; sA1 += ws*f01; sA2 += ws*f02; sA3 += ws*f03;
                bA0 += wb0*f00; bA1 += wb0*f01; bA2 += wb0*f02; bA3 += wb0*f03;
                sB0 += ws*f10; sB1 += ws*f11; sB2 += ws*f12; sB3 += ws*f13;
                bB0 += wb1*f10; bB1 += wb1*f11; bB2 += wb1*f12; bB3 += wb1*f13;
            }
        }
        __syncthreads();   // smH dead -> region A becomes accH

        // ---- normalized (s,b) vectors into accH [px][40] f16 ----
        *(half4*)(accH + px0l*40 + g*4) =
            (half4){(_Float16)(sA0*snI0), (_Float16)(sA1*snI0),
                    (_Float16)(sA2*snI0), (_Float16)(sA3*snI0)};
        *(half4*)(accH + px0l*40 + 20 + g*4) =
            (half4){(_Float16)(bA0*bnI0), (_Float16)(bA1*bnI0),
                    (_Float16)(bA2*bnI0), (_Float16)(bA3*bnI0)};
        *(half4*)(accH + (px0l+1)*40 + g*4) =
            (half4){(_Float16)(sB0*snI1), (_Float16)(sB1*snI1),
                    (_Float16)(sB2*snI1), (_Float16)(sB3*snI1)};
        *(half4*)(accH + (px0l+1)*40 + 20 + g*4) =
            (half4){(_Float16)(bB0*bnI1), (_Float16)(bB1*bnI1),
                    (_Float16)(bB2*bnI1), (_Float16)(bB3*bnI1)};
        __syncthreads();

        // ---- epilogue: q_k = u_k - M[k,:] . [s|b]  (M via uniform s_loads) ----
        float av0[40], av1[40];
        #pragma unroll
        for (int m = 0; m < 5; ++m) {
            const half8 t0 = ((const half8*)(accH + px0l*40))[m];
            const half8 t1 = ((const half8*)(accH + (px0l+1)*40))[m];
            #pragma unroll
            for (int i = 0; i < 8; ++i) { av0[8*m+i] = (float)t0[i]; av1[8*m+i] = (float)t1[i]; }
        }
        const float* Mg = M + gu * 160;          // rows 4g..4g+3
        float o0[4], o1[4];
        #pragma unroll
        for (int i = 0; i < 4; ++i) {
            const float* mk = Mg + i * 40;
            float pw0 = 0.f, pw1 = 0.f;
            #pragma unroll
            for (int c = 0; c < 40; ++c) { pw0 += mk[c]*av0[c]; pw1 += mk[c]*av1[c]; }
            o0[i] = uv0[i] - pw0;
            o1[i] = uv1[i] - pw1;
        }

        if (it == 4) {
            #pragma unroll
            for (int i = 0; i < 4; ++i) {
                const int ch = 4*g + i;
                if (ch < NC) {
                    out[(size_t)gp0 * NC + ch]       = o0[i];
                    out[(size_t)(gp0 + 1) * NC + ch] = o1[i];
                }
            }
        } else {
            float4* qdst = (it & 1) ? qB : qA;
            qdst[(size_t)gp0 * NG + g]       = make_float4(o0[0], o0[1], o0[2], o0[3]);
            qdst[(size_t)(gp0 + 1) * NG + g] = make_float4(o1[0], o1[1], o1[2], o1[3]);
        }
    }
}

extern "C" void kernel_launch(void* const* d_in, const int* in_sizes, int n_in,
                              void* d_out, int out_size, void* d_ws, size_t ws_size,
                              hipStream_t stream) {
    const float* u      = (const float*)d_in[0];
    const float* rgb    = (const float*)d_in[1];
    const float* sw     = (const float*)d_in[2];
    const float* bw     = (const float*)d_in[3];
    const float* compat = (const float*)d_in[4];
    float* out = (float*)d_out;

    float4*   qA  = (float4*)d_ws;                          // 4,096,000 B
    float4*   qB  = (float4*)((char*)d_ws + 4096000);       // 4,096,000 B
    float*    M   = (float*)((char*)d_ws + 8192000);        // 3,200 B
    unsigned* bar = (unsigned*)((char*)d_ws + 8195584);     // flag + counter

    prep_kernel<<<1, 800, 0, stream>>>(sw, bw, compat, M);
    crf_kernel<<<dim3(WW/TS, HH/TS, 2), dim3(NTHR), 0, stream>>>(
        u, rgb, M, qA, qB, bar, out);
}

// Round 7
// 200.083 us; speedup vs baseline: 1.8906x; 1.4388x over previous
//
#include <hip/hip_runtime.h>

// ConvCRF forward, MI355X — round 7: fused single-pass, batch-pair blocks,
// sm0-only exchange.
// R6 post-mortem: 232us crf == 170MB post-L2 traffic / 730 GB/s. Agent fences
// (full L2 wb/inv per barrier) destroy locality, and the q exchange read both
// batches' q per block (31 MB/iter). Fix: batch=2 softmax algebra:
//   sm1 = 1 - sm0   =>  only sm0 (f16, 1 MB) crosses blocks.
//   s_out1n = 1 - s_out0n (spatial norm is batch-indep)
//   b_out1n = 1 - (sum wb1*sm0)/bnorm1
//   pairwise1 = RS - Ms.s0n - Mb.b1x, RS[k] = sum_c (Ms+Mb)[k,c] (precomputed)
// q stays in registers (block owns both batches of its pixels; softmax is
// pointwise across batch). Coherent working set drops ~20x.
// Proven pieces kept: 200-block grid (R4/R6 co-residency scale), R6 barrier
// protocol (tid0 agent fences), iteration-invariant f16 bilateral weights,
// literal spatial weights, wave-uniform s_load matvec.

typedef __attribute__((ext_vector_type(4))) _Float16 half4;
typedef __attribute__((ext_vector_type(2))) _Float16 half2f;

#define HH 160
#define WW 160
#define NPIX (HH*WW)
#define NC 19
#define NG 5
#define SPAN 3
#define TR 8               // tile rows
#define TC 16              // tile cols
#define NPXT 128           // pixels per tile
#define LR 14              // TR + 2*SPAN
#define LC 22              // TC + 2*SPAN
#define LCP 24             // padded halo row stride (16-bank shift per row)
#define HSTRIDE (LR*LCP)   // 336
#define NHALO (LR*LC)      // 308
#define NBLK 200
#define NTHR 640
#define EPSF 1e-20f
#define MAGICV 0x5EEDF00Du

// LDS: region A time-shared: rgbL(2x336 f4=10752) -> smH(5x336 h4=13440)
//      -> accF(60x128 f32=30720). wbH separate.
#define SZ_A    30720
#define OFF_WB  SZ_A
#define LDS_TOT (SZ_A + 49*128*4)   // 55,808 B

__device__ __forceinline__ float fast_rcp(float x) { return __builtin_amdgcn_rcpf(x); }

// batch-0 softmax prob (batch axis has size 2)
__device__ __forceinline__ float smx0(float q0, float q1) {
    const float m  = fmaxf(q0, q1);
    const float e0 = __expf(q0 - m);
    const float e1 = __expf(q1 - m);
    return e0 * fast_rcp(e0 + e1);
}

__global__ __launch_bounds__(960) void prep_kernel(
        const float* __restrict__ sw, const float* __restrict__ bw,
        const float* __restrict__ compat, float* __restrict__ M) {
    const int e = threadIdx.x;            // 20 rows x 48 cols
    if (e >= 20 * 48) return;
    const int k = e / 48, c = e % 48;
    float acc = 0.0f;
    if (k < NC) {
        if (c < NC) {                      // Ms[k][c]
            for (int j = 0; j < NC; ++j) acc += compat[k*NC + j] * sw[j*NC + c];
        } else if (c >= 20 && c < 20 + NC) {   // Mb[k][c-20]
            const int cc = c - 20;
            for (int j = 0; j < NC; ++j) acc += compat[k*NC + j] * bw[j*NC + cc];
        } else if (c == 40) {              // RS[k] = sum_c (Ms+Mb)[k,c]
            for (int j = 0; j < NC; ++j) {
                float rs = 0.0f;
                for (int cc = 0; cc < NC; ++cc) rs += sw[j*NC + cc] + bw[j*NC + cc];
                acc += compat[k*NC + j] * rs;
            }
        }
    }
    M[e] = acc;   // pad rows/cols stay 0 -> pad channel masked in matvec
}

__global__ void __launch_bounds__(NTHR) crf_kernel(
        const float* __restrict__ u,      // (2,160,160,19)
        const float* __restrict__ rgb,    // (2,160,160,3)
        const float* __restrict__ M,      // (20,48): [Ms|Mb|RS|pad]
        half4* __restrict__ gsm,          // sm0 field: [g][NPIX] half4
        unsigned* __restrict__ bar,       // [0]=flag, [1]=counter
        float* __restrict__ out) {
    __shared__ __align__(16) char shm[LDS_TOT];
    float4*   rgbL = (float4*)shm;               // [b][HSTRIDE] (weight phase)
    half4*    smH  = (half4*)shm;                // [g][HSTRIDE] (tap phase)
    float*    accF = (float*)shm;                // [60][128]    (epilogue)
    unsigned* wbH  = (unsigned*)(shm + OFF_WB);  // [49][128] half2(wb0,wb1)

    const int tid = threadIdx.x;
    const int px  = tid & 127;
    const int g   = tid >> 7;                    // channel group, wave-uniform
    const int r   = px >> 4, c = px & 15;
    const int ti0 = blockIdx.y * TR, tj0 = blockIdx.x * TC;
    const int gp  = (ti0 + r) * WW + (tj0 + c);

    // ---- barrier init handshake (ws re-poisoned 0xAA before every launch) ----
    if ((blockIdx.x | blockIdx.y) == 0 && tid == 0) {
        __hip_atomic_store(&bar[1], 0u, __ATOMIC_RELAXED, __HIP_MEMORY_SCOPE_AGENT);
        __hip_atomic_store(&bar[0], MAGICV, __ATOMIC_RELEASE, __HIP_MEMORY_SCOPE_AGENT);
    }
    if (tid == 0) {
        while (__hip_atomic_load(&bar[0], __ATOMIC_ACQUIRE, __HIP_MEMORY_SCOPE_AGENT) != MAGICV)
            __builtin_amdgcn_s_sleep(2);
    }
    __syncthreads();

    // ---- phase 1: rgb halo, BOTH batches (scaled 1/160, .w = validity) ----
    for (int e = tid; e < 2 * NHALO; e += NTHR) {
        const int bb = e / NHALO, pos = e % NHALO;
        const int hr = pos / LC, hc = pos % LC;
        const int yi = ti0 - SPAN + hr, xj = tj0 - SPAN + hc;
        float4 rv = make_float4(0.f, 0.f, 0.f, 0.f);
        if (yi >= 0 && yi < HH && xj >= 0 && xj < WW) {
            const float* p = rgb + ((size_t)(bb * NPIX) + yi * WW + xj) * 3;
            rv = make_float4(p[0]*(1.f/160.f), p[1]*(1.f/160.f), p[2]*(1.f/160.f), 1.f);
        }
        rgbL[bb * HSTRIDE + hr * LCP + hc] = rv;
    }
    __syncthreads();

    // ---- phase 2: per-(px,tap) bilateral weights (both batches) + norms ----
    // All threads compute for their own px (g>0 redundant, one-time); g==0 writes.
    constexpr float WSPC[49] = {
        0.36787944f,0.48567179f,0.57375342f,0.60653066f,0.57375342f,0.48567179f,0.36787944f,
        0.48567179f,0.64118039f,0.75746513f,0.80073740f,0.75746513f,0.64118039f,0.48567179f,
        0.57375342f,0.75746513f,0.89483932f,0.94595947f,0.89483932f,0.75746513f,0.57375342f,
        0.60653066f,0.80073740f,0.94595947f,1.00000000f,0.94595947f,0.80073740f,0.60653066f,
        0.57375342f,0.75746513f,0.89483932f,0.94595947f,0.89483932f,0.75746513f,0.57375342f,
        0.48567179f,0.64118039f,0.75746513f,0.80073740f,0.75746513f,0.64118039f,0.48567179f,
        0.36787944f,0.48567179f,0.57375342f,0.60653066f,0.57375342f,0.48567179f,0.36787944f };

    const int ctr = (r + SPAN) * LCP + (c + SPAN);
    float snI, bnI0, bnI1;
    {
        const float4 cv0 = rgbL[ctr];
        const float4 cv1 = rgbL[HSTRIDE + ctr];
        float sn = 0.f, bn0 = 0.f, bn1 = 0.f;
        #pragma unroll
        for (int dx = -SPAN; dx <= SPAN; ++dx) {
            #pragma unroll
            for (int dy = -SPAN; dy <= SPAN; ++dy) {
                const int t = (dx+SPAN)*7 + (dy+SPAN);
                const int n = ctr + dx*LCP + dy;
                const float4 nv0 = rgbL[n];
                const float4 nv1 = rgbL[HSTRIDE + n];
                const float wsm = WSPC[t] * nv0.w;      // spatial mask (batch-indep)
                const float dr0 = cv0.x-nv0.x, dg0 = cv0.y-nv0.y, db0 = cv0.z-nv0.z;
                const float dr1 = cv1.x-nv1.x, dg1 = cv1.y-nv1.y, db1 = cv1.z-nv1.z;
                const float wb0 = wsm * __expf(-0.5f*(dr0*dr0+dg0*dg0+db0*db0));
                const float wb1 = wsm * __expf(-0.5f*(dr1*dr1+dg1*dg1+db1*db1));
                sn += wsm; bn0 += wb0; bn1 += wb1;
                if (g == 0) {
                    half2f hw = {(_Float16)wb0, (_Float16)wb1};
                    unsigned uw; __builtin_memcpy(&uw, &hw, 4);
                    wbH[t*NPXT + px] = uw;
                }
            }
        }
        snI = fast_rcp(sn + EPSF);
        bnI0 = fast_rcp(bn0 + EPSF);
        bnI1 = fast_rcp(bn1 + EPSF);
    }

    // ---- one-time: own unaries (both batches), initial sm0 ----
    float uv0[4], uv1[4];
    #pragma unroll
    for (int i = 0; i < 4; ++i) {
        const int ch = 4*g + i;
        uv0[i] = (ch < NC) ? u[(size_t)gp * NC + ch] : 0.0f;
        uv1[i] = (ch < NC) ? u[((size_t)NPIX + gp) * NC + ch] : 0.0f;
    }
    {
        half4 sh;
        #pragma unroll
        for (int i = 0; i < 4; ++i) sh[i] = (_Float16)smx0(uv0[i], uv1[i]);
        gsm[g * NPIX + gp] = sh;
    }

    for (int it = 0; it < 5; ++it) {
        // ---- grid barrier: publish gsm, wait all, invalidate stale lines ----
        __syncthreads();
        if (tid == 0) {
            __threadfence();
            __hip_atomic_fetch_add(&bar[1], 1u, __ATOMIC_ACQ_REL, __HIP_MEMORY_SCOPE_AGENT);
            while (__hip_atomic_load(&bar[1], __ATOMIC_ACQUIRE, __HIP_MEMORY_SCOPE_AGENT)
                   < (unsigned)(NBLK * (it + 1)))
                __builtin_amdgcn_s_sleep(2);
            __threadfence();
        }
        __syncthreads();

        // ---- stage sm0 halo: 5 groups x 308 positions, f16 half4 ----
        for (int e = tid; e < NG * NHALO; e += NTHR) {
            const int sg = e / NHALO, pos = e % NHALO;
            const int hr = pos / LC, hc = pos % LC;
            const int yi = ti0 - SPAN + hr, xj = tj0 - SPAN + hc;
            half4 hv = (half4)(_Float16)0.0f;
            if (yi >= 0 && yi < HH && xj >= 0 && xj < WW)
                hv = gsm[sg * NPIX + yi * WW + xj];
            smH[sg * HSTRIDE + hr * LCP + hc] = hv;
        }
        __syncthreads();

        // ---- 49 taps: s (shared), b0, b1 accumulation; zero exp, zero masks ----
        float sA[4] = {0,0,0,0}, bA0[4] = {0,0,0,0}, bA1[4] = {0,0,0,0};
        const half4* pl = smH + g * HSTRIDE;
        #pragma unroll
        for (int dx = -SPAN; dx <= SPAN; ++dx) {
            #pragma unroll
            for (int dy = -SPAN; dy <= SPAN; ++dy) {
                const int t = (dx+SPAN)*7 + (dy+SPAN);
                const unsigned uw = wbH[t*NPXT + px];
                half2f hw; __builtin_memcpy(&hw, &uw, 4);
                const float w0 = (float)hw.x, w1 = (float)hw.y;
                const half4 v = pl[ctr + dx*LCP + dy];
                #pragma unroll
                for (int i = 0; i < 4; ++i) {
                    const float f = (float)v[i];
                    sA[i]  += WSPC[t] * f;
                    bA0[i] += w0 * f;
                    bA1[i] += w1 * f;
                }
            }
        }
        __syncthreads();   // smH dead -> region A becomes accF

        // ---- exchange normalized vectors: accF[vec*20+ch][px] ----
        #pragma unroll
        for (int i = 0; i < 4; ++i) {
            accF[(4*g + i) * NPXT + px]        = sA[i]  * snI;
            accF[(20 + 4*g + i) * NPXT + px]   = bA0[i] * bnI0;
            accF[(40 + 4*g + i) * NPXT + px]   = bA1[i] * bnI1;
        }
        __syncthreads();

        // ---- matvec: t1=Ms.s0n, t2=Mb.b0n, t3=Mb.b1x (wave-uniform s_loads) ----
        const int ku = 4 * __builtin_amdgcn_readfirstlane(g);
        float t1[4] = {0,0,0,0}, t2[4] = {0,0,0,0}, t3[4] = {0,0,0,0};
        #pragma unroll
        for (int cc = 0; cc < 20; ++cc) {      // col 19 of Ms/Mb is 0 (pad-safe)
            const float sv  = accF[cc * NPXT + px];
            const float b0v = accF[(20 + cc) * NPXT + px];
            const float b1v = accF[(40 + cc) * NPXT + px];
            #pragma unroll
            for (int i = 0; i < 4; ++i) {
                const float* mk = M + (ku + i) * 48;
                t1[i] += mk[cc] * sv;
                t2[i] += mk[20 + cc] * b0v;
                t3[i] += mk[20 + cc] * b1v;
            }
        }

        // q0 = u0 - Ms.s0n - Mb.b0n ; q1 = u1 - RS + Ms.s0n + Mb.b1x
        float q0v[4], q1v[4];
        #pragma unroll
        for (int i = 0; i < 4; ++i) {
            const float rs = M[(ku + i) * 48 + 40];
            q0v[i] = uv0[i] - t1[i] - t2[i];
            q1v[i] = uv1[i] - rs + t1[i] + t3[i];
        }

        if (it == 4) {
            #pragma unroll
            for (int i = 0; i < 4; ++i) {
                const int ch = 4*g + i;
                if (ch < NC) {
                    out[(size_t)gp * NC + ch]            = q0v[i];
                    out[((size_t)NPIX + gp) * NC + ch]   = q1v[i];
                }
            }
        } else {
            half4 sh;
            #pragma unroll
            for (int i = 0; i < 4; ++i) sh[i] = (_Float16)smx0(q0v[i], q1v[i]);
            gsm[g * NPIX + gp] = sh;
        }
    }
}

extern "C" void kernel_launch(void* const* d_in, const int* in_sizes, int n_in,
                              void* d_out, int out_size, void* d_ws, size_t ws_size,
                              hipStream_t stream) {
    const float* u      = (const float*)d_in[0];
    const float* rgb    = (const float*)d_in[1];
    const float* sw     = (const float*)d_in[2];
    const float* bw     = (const float*)d_in[3];
    const float* compat = (const float*)d_in[4];
    float* out = (float*)d_out;

    half4*    gsm = (half4*)d_ws;                           // 1,024,000 B
    float*    M   = (float*)((char*)d_ws + 1024000);        // 3,840 B
    unsigned* bar = (unsigned*)((char*)d_ws + 1032192);     // flag + counter

    prep_kernel<<<1, 960, 0, stream>>>(sw, bw, compat, M);
    crf_kernel<<<dim3(WW/TC, HH/TR, 1), dim3(NTHR), 0, stream>>>(
        u, rgb, M, gsm, bar, out);
}

// Round 8
// 136.203 us; speedup vs baseline: 2.7774x; 1.4690x over previous
//
#include <hip/hip_runtime.h>

// ConvCRF forward, MI355X — round 8: fence-free grid barrier via fine-grained
// coherent exchange.
// R7 post-mortem: 137us crf @ only 25MB traffic = latency-bound. Cost = 200x
// buffer_wbl2 + 200x buffer_inv per iteration (tid0 __threadfence pair) +
// post-inv cold-cache refetch at ~900cyc with 2.5 waves/SIMD.
// Fix: the ONLY cross-block field is gsm (sm0, half4 = 8B). Access it purely
// with RELAXED AGENT-scope atomics (global_load/store sc0 sc1: bypass the
// non-coherent per-XCD L2, coherent at the IF-cache point — same path the
// barrier counter already uses). Then the barrier needs NO cache maintenance:
// __syncthreads (drains vmcnt -> sc1 stores visible) + relaxed counter.
// L1/L2-resident state (M, wbH is LDS, rgb, u) survives all iterations.
// Also: staging loads batched 3-in-flight; one-time weight exp split across
// the 5 channel groups (norms re-summed from wbH; spatial part needs no exp).
// Numerics identical to R7 (passed, absmax 0.031 vs 0.119 threshold):
//   sm1 = 1-sm0; s_out1n = 1-s_out0n; b_out1n = 1-(sum wb1*sm0)*bnI1;
//   pairwise1 = RS - Ms.s0n - Mb.b1x with RS[k] = sum_c(Ms+Mb)[k,c].

typedef __attribute__((ext_vector_type(4))) _Float16 half4;
typedef __attribute__((ext_vector_type(2))) _Float16 half2f;

#define HH 160
#define WW 160
#define NPIX (HH*WW)
#define NC 19
#define NG 5
#define SPAN 3
#define TR 8
#define TC 16
#define NPXT 128
#define LR 14              // TR + 2*SPAN
#define LC 22              // TC + 2*SPAN
#define LCP 24             // padded halo row stride
#define HSTRIDE (LR*LCP)   // 336
#define NHALO (LR*LC)      // 308
#define NBLK 200
#define NTHR 640
#define EPSF 1e-20f
#define MAGICV 0x5EEDF00Du

#define SZ_A    30720                    // rgbL(2x336 f4) -> smH(5x336 h4) -> accF(60x128 f32)
#define OFF_WB  SZ_A
#define LDS_TOT (SZ_A + 49*128*4)        // 55,808 B

__device__ __forceinline__ float fast_rcp(float x) { return __builtin_amdgcn_rcpf(x); }

__device__ __forceinline__ float smx0(float q0, float q1) {
    const float m  = fmaxf(q0, q1);
    const float e0 = __expf(q0 - m);
    const float e1 = __expf(q1 - m);
    return e0 * fast_rcp(e0 + e1);
}

__global__ __launch_bounds__(960) void prep_kernel(
        const float* __restrict__ sw, const float* __restrict__ bw,
        const float* __restrict__ compat, float* __restrict__ M) {
    const int e = threadIdx.x;            // 20 rows x 48 cols
    if (e >= 20 * 48) return;
    const int k = e / 48, c = e % 48;
    float acc = 0.0f;
    if (k < NC) {
        if (c < NC) {
            for (int j = 0; j < NC; ++j) acc += compat[k*NC + j] * sw[j*NC + c];
        } else if (c >= 20 && c < 20 + NC) {
            const int cc = c - 20;
            for (int j = 0; j < NC; ++j) acc += compat[k*NC + j] * bw[j*NC + cc];
        } else if (c == 40) {
            for (int j = 0; j < NC; ++j) {
                float rs = 0.0f;
                for (int cc = 0; cc < NC; ++cc) rs += sw[j*NC + cc] + bw[j*NC + cc];
                acc += compat[k*NC + j] * rs;
            }
        }
    }
    M[e] = acc;
}

__global__ void __launch_bounds__(NTHR) crf_kernel(
        const float* __restrict__ u,
        const float* __restrict__ rgb,
        const float* __restrict__ M,               // (20,48): [Ms|Mb|RS|pad]
        unsigned long long* __restrict__ gsm,      // sm0 field [g][NPIX], half4-as-u64
        unsigned* __restrict__ bar,
        float* __restrict__ out) {
    __shared__ __align__(16) char shm[LDS_TOT];
    float4*   rgbL = (float4*)shm;
    half4*    smH  = (half4*)shm;
    float*    accF = (float*)shm;
    unsigned* wbH  = (unsigned*)(shm + OFF_WB);

    constexpr float WSPC[49] = {
        0.36787944f,0.48567179f,0.57375342f,0.60653066f,0.57375342f,0.48567179f,0.36787944f,
        0.48567179f,0.64118039f,0.75746513f,0.80073740f,0.75746513f,0.64118039f,0.48567179f,
        0.57375342f,0.75746513f,0.89483932f,0.94595947f,0.89483932f,0.75746513f,0.57375342f,
        0.60653066f,0.80073740f,0.94595947f,1.00000000f,0.94595947f,0.80073740f,0.60653066f,
        0.57375342f,0.75746513f,0.89483932f,0.94595947f,0.89483932f,0.75746513f,0.57375342f,
        0.48567179f,0.64118039f,0.75746513f,0.80073740f,0.75746513f,0.64118039f,0.48567179f,
        0.36787944f,0.48567179f,0.57375342f,0.60653066f,0.57375342f,0.48567179f,0.36787944f };

    const int tid = threadIdx.x;
    const int px  = tid & 127;
    const int g   = tid >> 7;
    const int r   = px >> 4, c = px & 15;
    const int ti0 = blockIdx.y * TR, tj0 = blockIdx.x * TC;
    const int gp  = (ti0 + r) * WW + (tj0 + c);
    const int ctr = (r + SPAN) * LCP + (c + SPAN);

    // ---- barrier init handshake (ws poisoned 0xAA before every launch) ----
    if ((blockIdx.x | blockIdx.y) == 0 && tid == 0) {
        __hip_atomic_store(&bar[1], 0u, __ATOMIC_RELAXED, __HIP_MEMORY_SCOPE_AGENT);
        __hip_atomic_store(&bar[0], MAGICV, __ATOMIC_RELEASE, __HIP_MEMORY_SCOPE_AGENT);
    }
    if (tid == 0) {
        while (__hip_atomic_load(&bar[0], __ATOMIC_ACQUIRE, __HIP_MEMORY_SCOPE_AGENT) != MAGICV)
            __builtin_amdgcn_s_sleep(2);
    }
    __syncthreads();

    // ---- phase 1: rgb halo, both batches ----
    for (int e = tid; e < 2 * NHALO; e += NTHR) {
        const int bb = e / NHALO, pos = e % NHALO;
        const int hr = pos / LC, hc = pos % LC;
        const int yi = ti0 - SPAN + hr, xj = tj0 - SPAN + hc;
        float4 rv = make_float4(0.f, 0.f, 0.f, 0.f);
        if ((unsigned)yi < HH && (unsigned)xj < WW) {
            const float* p = rgb + ((size_t)(bb * NPIX) + yi * WW + xj) * 3;
            rv = make_float4(p[0]*(1.f/160.f), p[1]*(1.f/160.f), p[2]*(1.f/160.f), 1.f);
        }
        rgbL[bb * HSTRIDE + hr * LCP + hc] = rv;
    }
    __syncthreads();

    // ---- phase 2a: bilateral weights, tap-subset per channel group ----
    {
        const float4 cv0 = rgbL[ctr];
        const float4 cv1 = rgbL[HSTRIDE + ctr];
        const int tapb = g * 10;
        const int ntap = (g == 4) ? 9 : 10;
        for (int i = 0; i < ntap; ++i) {
            const int t = tapb + i;
            const int dx = t / 7 - SPAN, dy = t % 7 - SPAN;
            const int n = ctr + dx * LCP + dy;
            const float4 nv0 = rgbL[n];
            const float4 nv1 = rgbL[HSTRIDE + n];
            const float wsm = __expf(-(float)(dx*dx + dy*dy) * (1.f/18.f)) * nv0.w;
            const float dr0 = cv0.x-nv0.x, dg0 = cv0.y-nv0.y, db0 = cv0.z-nv0.z;
            const float dr1 = cv1.x-nv1.x, dg1 = cv1.y-nv1.y, db1 = cv1.z-nv1.z;
            const float wb0 = wsm * __expf(-0.5f*(dr0*dr0+dg0*dg0+db0*db0));
            const float wb1 = wsm * __expf(-0.5f*(dr1*dr1+dg1*dg1+db1*db1));
            half2f hw = {(_Float16)wb0, (_Float16)wb1};
            unsigned uw; __builtin_memcpy(&uw, &hw, 4);
            wbH[t*NPXT + px] = uw;
        }
    }
    __syncthreads();

    // ---- phase 2b: per-pixel inverse norms (no exp; wb re-summed from LDS) ----
    float snI, bnI0, bnI1;
    {
        float sn = 0.f, bn0 = 0.f, bn1 = 0.f;
        #pragma unroll
        for (int dx = -SPAN; dx <= SPAN; ++dx) {
            #pragma unroll
            for (int dy = -SPAN; dy <= SPAN; ++dy) {
                const int t = (dx+SPAN)*7 + (dy+SPAN);
                const int yi = ti0 + r + dx, xj = tj0 + c + dy;
                const bool ok = ((unsigned)yi < HH) && ((unsigned)xj < WW);
                sn += ok ? WSPC[t] : 0.0f;
                const unsigned uw = wbH[t*NPXT + px];
                half2f hw; __builtin_memcpy(&hw, &uw, 4);
                bn0 += (float)hw.x; bn1 += (float)hw.y;
            }
        }
        snI  = fast_rcp(sn + EPSF);
        bnI0 = fast_rcp(bn0 + EPSF);
        bnI1 = fast_rcp(bn1 + EPSF);
    }

    // ---- one-time: own unaries (both batches), publish initial sm0 ----
    float uv0[4], uv1[4];
    #pragma unroll
    for (int i = 0; i < 4; ++i) {
        const int ch = 4*g + i;
        uv0[i] = (ch < NC) ? u[(size_t)gp * NC + ch] : 0.0f;
        uv1[i] = (ch < NC) ? u[((size_t)NPIX + gp) * NC + ch] : 0.0f;
    }
    {
        half4 sh;
        #pragma unroll
        for (int i = 0; i < 4; ++i) sh[i] = (_Float16)smx0(uv0[i], uv1[i]);
        unsigned long long u64; __builtin_memcpy(&u64, &sh, 8);
        __hip_atomic_store(&gsm[g * NPIX + gp], u64, __ATOMIC_RELAXED, __HIP_MEMORY_SCOPE_AGENT);
    }

    for (int it = 0; it < 5; ++it) {
        // ---- fence-free grid barrier ----
        // __syncthreads drains each wave's vmcnt -> all sc1 gsm stores are at the
        // coherent point before any lane arrives; counter is relaxed agent atomic;
        // post-barrier gsm loads bypass L1/L2 (sc0 sc1) so no invalidate needed.
        __syncthreads();
        if (tid == 0) {
            __hip_atomic_fetch_add(&bar[1], 1u, __ATOMIC_RELAXED, __HIP_MEMORY_SCOPE_AGENT);
            while (__hip_atomic_load(&bar[1], __ATOMIC_RELAXED, __HIP_MEMORY_SCOPE_AGENT)
                   < (unsigned)(NBLK * (it + 1)))
                __builtin_amdgcn_s_sleep(2);
        }
        __syncthreads();

        // ---- stage sm0 halo (batched loads -> LDS) ----
        unsigned long long raw[3];
        int dst[3];
        #pragma unroll
        for (int k2 = 0; k2 < 3; ++k2) {
            const int e = tid + NTHR * k2;
            raw[k2] = 0ull; dst[k2] = -1;
            if (e < NG * NHALO) {
                const int sg = e / NHALO, pos = e - sg * NHALO;
                const int hr = pos / LC, hc = pos - hr * LC;
                const int yi = ti0 - SPAN + hr, xj = tj0 - SPAN + hc;
                dst[k2] = sg * HSTRIDE + hr * LCP + hc;
                if ((unsigned)yi < HH && (unsigned)xj < WW)
                    raw[k2] = __hip_atomic_load(&gsm[sg * NPIX + yi * WW + xj],
                                                __ATOMIC_RELAXED, __HIP_MEMORY_SCOPE_AGENT);
            }
        }
        #pragma unroll
        for (int k2 = 0; k2 < 3; ++k2) {
            if (dst[k2] >= 0) {
                half4 hv; __builtin_memcpy(&hv, &raw[k2], 8);
                smH[dst[k2]] = hv;
            }
        }
        __syncthreads();

        // ---- 49 taps: s (shared weight), b0, b1; zero exp, zero masks ----
        float sA[4] = {0,0,0,0}, bA0[4] = {0,0,0,0}, bA1[4] = {0,0,0,0};
        const half4* pl = smH + g * HSTRIDE;
        #pragma unroll
        for (int dx = -SPAN; dx <= SPAN; ++dx) {
            #pragma unroll
            for (int dy = -SPAN; dy <= SPAN; ++dy) {
                const int t = (dx+SPAN)*7 + (dy+SPAN);
                const unsigned uw = wbH[t*NPXT + px];
                half2f hw; __builtin_memcpy(&hw, &uw, 4);
                const float w0 = (float)hw.x, w1 = (float)hw.y;
                const half4 v = pl[ctr + dx*LCP + dy];
                #pragma unroll
                for (int i = 0; i < 4; ++i) {
                    const float f = (float)v[i];
                    sA[i]  += WSPC[t] * f;
                    bA0[i] += w0 * f;
                    bA1[i] += w1 * f;
                }
            }
        }
        __syncthreads();   // smH dead -> region A becomes accF

        // ---- exchange normalized vectors: accF[vec*20+ch][px] ----
        #pragma unroll
        for (int i = 0; i < 4; ++i) {
            accF[(4*g + i) * NPXT + px]      = sA[i]  * snI;
            accF[(20 + 4*g + i) * NPXT + px] = bA0[i] * bnI0;
            accF[(40 + 4*g + i) * NPXT + px] = bA1[i] * bnI1;
        }
        __syncthreads();

        // ---- matvec: t1=Ms.s0n, t2=Mb.b0n, t3=Mb.b1x (wave-uniform s_loads) ----
        const int ku = 4 * __builtin_amdgcn_readfirstlane(g);
        float t1[4] = {0,0,0,0}, t2[4] = {0,0,0,0}, t3[4] = {0,0,0,0};
        #pragma unroll
        for (int cc = 0; cc < 20; ++cc) {
            const float sv  = accF[cc * NPXT + px];
            const float b0v = accF[(20 + cc) * NPXT + px];
            const float b1v = accF[(40 + cc) * NPXT + px];
            #pragma unroll
            for (int i = 0; i < 4; ++i) {
                const float* mk = M + (ku + i) * 48;
                t1[i] += mk[cc] * sv;
                t2[i] += mk[20 + cc] * b0v;
                t3[i] += mk[20 + cc] * b1v;
            }
        }

        float q0v[4], q1v[4];
        #pragma unroll
        for (int i = 0; i < 4; ++i) {
            const float rs = M[(ku + i) * 48 + 40];
            q0v[i] = uv0[i] - t1[i] - t2[i];
            q1v[i] = uv1[i] - rs + t1[i] + t3[i];
        }

        if (it == 4) {
            #pragma unroll
            for (int i = 0; i < 4; ++i) {
                const int ch = 4*g + i;
                if (ch < NC) {
                    out[(size_t)gp * NC + ch]          = q0v[i];
                    out[((size_t)NPIX + gp) * NC + ch] = q1v[i];
                }
            }
        } else {
            half4 sh;
            #pragma unroll
            for (int i = 0; i < 4; ++i) sh[i] = (_Float16)smx0(q0v[i], q1v[i]);
            unsigned long long u64; __builtin_memcpy(&u64, &sh, 8);
            __hip_atomic_store(&gsm[g * NPIX + gp], u64, __ATOMIC_RELAXED, __HIP_MEMORY_SCOPE_AGENT);
        }
    }
}

extern "C" void kernel_launch(void* const* d_in, const int* in_sizes, int n_in,
                              void* d_out, int out_size, void* d_ws, size_t ws_size,
                              hipStream_t stream) {
    const float* u      = (const float*)d_in[0];
    const float* rgb    = (const float*)d_in[1];
    const float* sw     = (const float*)d_in[2];
    const float* bw     = (const float*)d_in[3];
    const float* compat = (const float*)d_in[4];
    float* out = (float*)d_out;

    unsigned long long* gsm = (unsigned long long*)d_ws;     // 1,024,000 B
    float*    M   = (float*)((char*)d_ws + 1024000);         // 3,840 B
    unsigned* bar = (unsigned*)((char*)d_ws + 1032192);      // flag + counter

    prep_kernel<<<1, 960, 0, stream>>>(sw, bw, compat, M);
    crf_kernel<<<dim3(WW/TC, HH/TR, 1), dim3(NTHR), 0, stream>>>(
        u, rgb, M, gsm, bar, out);
}